// Round 16
// baseline (217.884 us; speedup 1.0000x reference)
//
#include <hip/hip_runtime.h>
#include <hip/hip_fp16.h>

#define N_NODES 50000
#define N_EDGES 800000
#define N_GRAPHS 64
#define N_PAD 50048

#define CB 256                              // coarse-pass blocks
#define EPB (N_EDGES / CB)                  // 3125 edges per block (exact)
#define NBUCKET ((N_NODES + 255) / 256)     // 196 coarse buckets (dst>>8)
#define ECAP 6144                           // LDS stage cap per bucket (mean 4082, 14 sigma)

typedef _Float16 f16x8 __attribute__((ext_vector_type(8)));
typedef float f32x4 __attribute__((ext_vector_type(4)));

struct H8 { __half2 a, b, c, d; };

// ---------------- hist + prep: coarse histogram to counts matrix; weight
// transpose->fp16 and pool zeroing folded in (disjoint index ranges) ----------------

__global__ __launch_bounds__(256) void k_hist_prep(
        const int* __restrict__ dst, int* __restrict__ counts,
        const float* __restrict__ W1, const float* __restrict__ W2,
        _Float16* __restrict__ Wt1, _Float16* __restrict__ Wt2,
        float* __restrict__ psum, float* __restrict__ pmax) {
    __shared__ int hist[256];
    int t = threadIdx.x, b = blockIdx.x;
    hist[t] = 0;
    // prep chores (spread over the grid by global id)
    int gid = b * 256 + t;
    if (gid < 128 * 64) {                    // Wt1[n*64+k] = W1[k*128+n]
        int n = gid >> 6, k = gid & 63;
        Wt1[gid] = (_Float16)W1[k * 128 + n];
    } else if (gid < 128 * 64 + 128 * 128) { // Wt2[n*128+k] = W2[k*128+n]
        int j = gid - 128 * 64;
        int n = j >> 7, k = j & 127;
        Wt2[j] = (_Float16)W2[k * 128 + n];
    }
    if (gid < N_GRAPHS * 128) { psum[gid] = 0.f; pmax[gid] = 0.f; }
    __syncthreads();
    int e0 = b * EPB;
    for (int e = e0 + t; e < e0 + EPB; e += 256)
        atomicAdd(&hist[dst[e] >> 8], 1);
    __syncthreads();
    for (int i = t; i < NBUCKET; i += 256)
        counts[i * CB + b] = hist[i];        // [bucket][block], no atomics
}

// ---------------- one block: totals, bucket scan, per-(bucket,block) bases, pcnt ----

__global__ __launch_bounds__(256) void k_scan(
        const int* __restrict__ counts, int* __restrict__ cbase,
        int* __restrict__ bucket_base, const int* __restrict__ batch,
        float* __restrict__ pcnt) {
    __shared__ int sh[256];
    __shared__ int lb[N_GRAPHS + 1];
    int t = threadIdx.x;
    int tot = 0;
    if (t < NBUCKET) {
#pragma unroll 8
        for (int b = 0; b < CB; b++) tot += counts[t * CB + b];
    }
    sh[t] = tot;
    __syncthreads();
    for (int off = 1; off < 256; off <<= 1) {
        int u = (t >= off) ? sh[t - off] : 0;
        __syncthreads();
        sh[t] += u;
        __syncthreads();
    }
    int base = sh[t] - tot;  // exclusive over buckets
    if (t < NBUCKET) {
        bucket_base[t] = base;
        int run = base;
#pragma unroll 4
        for (int b = 0; b < CB; b++) {
            int c = counts[t * CB + b];
            cbase[t * CB + b] = run;         // exclusive per block within bucket
            run += c;
        }
    }
    if (t == 0) bucket_base[NBUCKET] = N_EDGES;
    // pcnt[g] via lower_bound on sorted batch — zero atomics
    if (t <= N_GRAPHS) {
        int lo = 0, hi = N_NODES;
        while (lo < hi) {
            int mid = (lo + hi) >> 1;
            if (batch[mid] < t) lo = mid + 1; else hi = mid;
        }
        lb[t] = lo;
    }
    __syncthreads();
    if (t < N_GRAPHS) pcnt[t] = (float)(lb[t + 1] - lb[t]);
}

// ---------------- single-pass scatter: bases from cbase (no hist recompute,
// no global atomics); packed ((dst&255)<<16 | src) ----------------

__global__ __launch_bounds__(256) void k_scatter(
        const int* __restrict__ src, const int* __restrict__ dst,
        const int* __restrict__ cbase, unsigned int* __restrict__ esort) {
    __shared__ int cur[NBUCKET];
    int t = threadIdx.x, b = blockIdx.x;
    for (int i = t; i < NBUCKET; i += 256) cur[i] = cbase[i * CB + b];
    __syncthreads();
    int e0 = b * EPB;
    for (int e = e0 + t; e < e0 + EPB; e += 256) {
        int d = dst[e];
        int slot = atomicAdd(&cur[d >> 8], 1);
        esort[slot] = ((unsigned)(d & 255) << 16) | (unsigned)src[e];  // src < 2^16
    }
}

// one block per bucket: stage esort range in LDS (single global read), fine hist ->
// row_ptr/dinv, cursor fill of col; fused input projection
__global__ __launch_bounds__(256) void k_fine_fill_proj(
        const unsigned int* __restrict__ esort, const int* __restrict__ bucket_base,
        int* __restrict__ col, int* __restrict__ row_ptr, float* __restrict__ dinv,
        const float* __restrict__ x, const float* __restrict__ W_in,
        const float* __restrict__ b_in, _Float16* __restrict__ g0) {
    __shared__ int hist[256];
    __shared__ int sc[256];
    __shared__ int cur[256];
    __shared__ unsigned es[ECAP];
    int t = threadIdx.x, b = blockIdx.x;
    hist[t] = 0;
    __syncthreads();
    int base = bucket_base[b], end = bucket_base[b + 1];
    int cnt = end - base;
    int stg = cnt < ECAP ? cnt : ECAP;
    for (int i = t; i < stg; i += 256) {
        unsigned pk = esort[base + i];
        es[i] = pk;
        atomicAdd(&hist[(pk >> 16) & 255], 1);
    }
    for (int i = ECAP + t; i < cnt; i += 256)  // overflow path (statistically never)
        atomicAdd(&hist[(esort[base + i] >> 16) & 255], 1);
    __syncthreads();
    int v = hist[t];
    sc[t] = v;
    __syncthreads();
    for (int off = 1; off < 256; off <<= 1) {
        int u = (t >= off) ? sc[t - off] : 0;
        __syncthreads();
        sc[t] += u;
        __syncthreads();
    }
    int start = base + sc[t] - v;
    cur[t] = start;
    int node = b * 256 + t;
    float di = rsqrtf((float)(v + 1));  // +1 self-loop
    if (node < N_NODES) {
        row_ptr[node] = start;
        dinv[node] = di;
    }
    if (b == 0 && t == 0) row_ptr[N_NODES] = N_EDGES;
    __syncthreads();
    for (int i = t; i < stg; i += 256) {
        unsigned pk = es[i];
        int slot = atomicAdd(&cur[(pk >> 16) & 255], 1);
        col[slot] = (int)(pk & 0xffffu);
    }
    for (int i = ECAP + t; i < cnt; i += 256) {
        unsigned pk = esort[base + i];
        int slot = atomicAdd(&cur[(pk >> 16) & 255], 1);
        col[slot] = (int)(pk & 0xffffu);
    }
    // fused input projection for this block's node
    if (node < N_NODES) {
        float xr[6];
#pragma unroll
        for (int k = 0; k < 6; k++) xr[k] = x[node * 6 + k];
#pragma unroll
        for (int oc = 0; oc < 8; oc++) {  // 8 octets of 8 cols
            f16x8 o;
#pragma unroll
            for (int j = 0; j < 8; j++) {
                int cl = oc * 8 + j;
                float acc = b_in[cl];
#pragma unroll
                for (int k = 0; k < 6; k++) acc += xr[k] * W_in[k * 64 + cl];
                o[j] = (_Float16)(acc * di);
            }
            *(f16x8*)&g0[(size_t)node * 64 + oc * 8] = o;
        }
    }
}

// ---------------- fused gather + MFMA GEMM (+ optional fused pooling) ----------------
// ROWS=16 (K=128): 3125 blocks, 16 threads/row gather; wave w -> cols w*32..+32 (2 tiles)
// ROWS=32 (K=64): 1563 blocks, 8 threads/row gather; wave w -> rows (w&1)*16, cols (w>>1)*64
// POOL: stage epilogue values in LDS, column-threads reduce over the block's rows
// (batch sorted -> 1-2 graphs/block) and flush via atomics. No global h2 at all.
template <int K, int ROWS, bool HALF_OUT, bool POOL>
__global__ __launch_bounds__(256, 8) void k_gnn(
        const _Float16* __restrict__ g, const int* __restrict__ row_ptr,
        const int* __restrict__ col, const _Float16* __restrict__ Wt_h,
        const float* __restrict__ b, const float* __restrict__ dinv,
        void* __restrict__ outp, const int* __restrict__ batch,
        float* __restrict__ psum, float* __restrict__ pmax, int n) {
    constexpr int KP = K + 8;
    constexpr int TPR = 256 / ROWS;   // threads per row (16 or 8)
    constexpr int CO8 = K / 8;        // H8 chunks per row
    static_assert(K / TPR == 8, "8 channels per gather thread");
    constexpr int S_BYTES = ROWS * KP * 2;
    constexpr int H_BYTES = POOL ? ROWS * 128 * 4 : 0;
    constexpr int SMEM = S_BYTES > H_BYTES ? S_BYTES : H_BYTES;
    __shared__ __align__(16) char smem[SMEM];
    _Float16* Sl = (_Float16*)smem;
    float* Hs = (float*)smem;         // aliases Sl; used only after Sl is dead
    int t = threadIdx.x;

    // gather phase (4 loads in flight, 2 accumulator sets)
    {
        int row_local = t / TPR;
        int ck = t % TPR;             // which H8 chunk of the row
        int row = blockIdx.x * ROWS + row_local;
        float accA[8] = {};
        float accB[8] = {};
        const H8* gb = (const H8*)g;
        auto addv = [](float* acc, H8 v) {
            float2 f;
            f = __half22float2(v.a); acc[0] += f.x; acc[1] += f.y;
            f = __half22float2(v.b); acc[2] += f.x; acc[3] += f.y;
            f = __half22float2(v.c); acc[4] += f.x; acc[5] += f.y;
            f = __half22float2(v.d); acc[6] += f.x; acc[7] += f.y;
        };
        if (row < n) {
            addv(accA, gb[(size_t)row * CO8 + ck]);  // self term
            int e = row_ptr[row], e1 = row_ptr[row + 1];
            for (; e + 3 < e1; e += 4) {
                int c0 = col[e], c1 = col[e + 1], c2 = col[e + 2], c3 = col[e + 3];
                H8 v0 = gb[(size_t)c0 * CO8 + ck];
                H8 v1 = gb[(size_t)c1 * CO8 + ck];
                H8 v2 = gb[(size_t)c2 * CO8 + ck];
                H8 v3 = gb[(size_t)c3 * CO8 + ck];
                addv(accA, v0);
                addv(accB, v1);
                addv(accA, v2);
                addv(accB, v3);
            }
            if (e + 1 < e1) {
                H8 v0 = gb[(size_t)col[e] * CO8 + ck];
                H8 v1 = gb[(size_t)col[e + 1] * CO8 + ck];
                addv(accA, v0);
                addv(accB, v1);
                e += 2;
            }
            if (e < e1) addv(accA, gb[(size_t)col[e] * CO8 + ck]);
        }
        f16x8 o;
#pragma unroll
        for (int q = 0; q < 8; q++) o[q] = (_Float16)(accA[q] + accB[q]);
        *(f16x8*)&Sl[row_local * KP + ck * 8] = o;
    }
    __syncthreads();

    // MFMA phase
    int wave = t >> 6;
    int lane = t & 63;
    int m = lane & 15;
    int quad = lane >> 4;
    constexpr int COLT = (ROWS == 16) ? 2 : 4;  // column tiles per wave
    int col_base = (ROWS == 16) ? wave * 32 : (wave >> 1) * 64;
    int rbl = (ROWS == 16) ? 0 : (wave & 1) * 16;
    int wrow0 = blockIdx.x * ROWS + rbl;

    f32x4 acc[COLT] = {};
#pragma unroll
    for (int k0 = 0; k0 < K; k0 += 32) {
        f16x8 a = *(const f16x8*)&Sl[(rbl + m) * KP + k0 + quad * 8];
#pragma unroll
        for (int ct = 0; ct < COLT; ct++) {
            f16x8 bw = *(const f16x8*)(Wt_h + (size_t)(col_base + ct * 16 + m) * K + k0 + quad * 8);
            acc[ct] = __builtin_amdgcn_mfma_f32_16x16x32_f16(a, bw, acc[ct], 0, 0, 0);
        }
    }

    if (!POOL) {
#pragma unroll
        for (int r = 0; r < 4; r++) {
            int row = wrow0 + quad * 4 + r;
            if (row < n) {
                float di = dinv[row];
#pragma unroll
                for (int ct = 0; ct < COLT; ct++) {
                    int colb = col_base + ct * 16 + m;
                    float v = fmaxf(di * acc[ct][r] + b[colb], 0.f);
                    if (HALF_OUT)
                        ((_Float16*)outp)[(size_t)row * 128 + colb] = (_Float16)(v * di);
                    else
                        ((float*)outp)[(size_t)row * 128 + colb] = v;
                }
            }
        }
    } else {
        // fused pooling epilogue (ROWS==16): stage into Hs, reduce by sorted batch
        __syncthreads();  // all Sl reads complete before overwriting smem
#pragma unroll
        for (int r = 0; r < 4; r++) {
            int rl = quad * 4 + r;
            int row = wrow0 + rl;
            float di = (row < n) ? dinv[row] : 0.f;
#pragma unroll
            for (int ct = 0; ct < COLT; ct++) {
                int colb = col_base + ct * 16 + m;
                float v = fmaxf(di * acc[ct][r] + b[colb], 0.f);
                Hs[rl * 128 + colb] = (row < n) ? v : 0.f;
            }
        }
        __syncthreads();
        if (t < 128) {
            int colb = t;
            int row0b = blockIdx.x * ROWS;
            float s = 0.f, mx = 0.f;
            int gcur = batch[row0b < n ? row0b : (n - 1)];
            for (int rl = 0; rl < ROWS; rl++) {
                int row = row0b + rl;
                if (row >= n) break;
                int gi = batch[row];
                if (gi != gcur) {
                    atomicAdd(&psum[gcur * 128 + colb], s);
                    atomicMax((int*)&pmax[gcur * 128 + colb], __float_as_int(mx));
                    s = 0.f; mx = 0.f; gcur = gi;
                }
                float v = Hs[rl * 128 + colb];
                s += v;
                mx = fmaxf(mx, v);
            }
            atomicAdd(&psum[gcur * 128 + colb], s);
            atomicMax((int*)&pmax[gcur * 128 + colb], __float_as_int(mx));
        }
    }
}

// ---------------- final ----------------

__global__ void k_final(const float* __restrict__ psum, const float* __restrict__ pmax,
                        const float* __restrict__ pcnt, const float* __restrict__ Wp,
                        const float* __restrict__ bp, float* __restrict__ out) {
    int t = blockIdx.x * blockDim.x + threadIdx.x;
    if (t >= N_GRAPHS * 256) return;
    int g = t >> 8, j = t & 255;
    float inv = 1.0f / fmaxf(pcnt[g], 1.0f);
    float acc = bp[j];
#pragma unroll 4
    for (int k = 0; k < 128; k++) acc += (psum[g * 128 + k] * inv) * Wp[k * 256 + j];
#pragma unroll 4
    for (int k = 0; k < 128; k++) acc += pmax[g * 128 + k] * Wp[(128 + k) * 256 + j];
    out[t] = fmaxf(acc, 0.f);
}

extern "C" void kernel_launch(void* const* d_in, const int* in_sizes, int n_in,
                              void* d_out, int out_size, void* d_ws, size_t ws_size,
                              hipStream_t stream) {
    const int N = N_NODES, E = N_EDGES;
    const float* x    = (const float*)d_in[0];
    const int*   ei   = (const int*)d_in[1];
    const int*   src  = ei;
    const int*   dst  = ei + E;
    const int*   batch= (const int*)d_in[2];
    const float* W_in = (const float*)d_in[3];
    const float* b_in = (const float*)d_in[4];
    const float* W1   = (const float*)d_in[5];
    const float* b1   = (const float*)d_in[6];
    const float* W2   = (const float*)d_in[7];
    const float* b2   = (const float*)d_in[8];
    const float* Wp   = (const float*)d_in[9];
    const float* bp   = (const float*)d_in[10];
    float* out = (float*)d_out;

    char* p = (char*)d_ws;
    int* counts      = (int*)p;   p += NBUCKET * CB * 4;
    int* cbase       = (int*)p;   p += NBUCKET * CB * 4;
    int* bucket_base = (int*)p;   p += 256 * 4;
    int* row_ptr     = (int*)p;   p += (N_PAD + 64) * 4;
    int* col         = (int*)p;   p += (size_t)N_EDGES * 4;
    unsigned* esort  = (unsigned*)p; p += (size_t)N_EDGES * 4;
    float* dinv      = (float*)p; p += N_PAD * 4;
    _Float16* Wt1    = (_Float16*)p; p += 128 * 64 * 2;
    _Float16* Wt2    = (_Float16*)p; p += 128 * 128 * 2;
    _Float16* g0h    = (_Float16*)p; p += (size_t)N_PAD * 64 * 2;
    _Float16* g1h    = (_Float16*)p; p += (size_t)N_PAD * 128 * 2;
    float* psum      = (float*)p; p += N_GRAPHS * 128 * 4;
    float* pmax      = (float*)p; p += N_GRAPHS * 128 * 4;
    float* pcnt      = (float*)p;

    const int TB = 256;
    dim3 blk(TB);

    // CSR build + prep (counts matrix, no contended atomics, single dst pass)
    k_hist_prep<<<CB, blk, 0, stream>>>(dst, counts, W1, W2, Wt1, Wt2, psum, pmax);
    k_scan<<<1, blk, 0, stream>>>(counts, cbase, bucket_base, batch, pcnt);
    k_scatter<<<CB, blk, 0, stream>>>(src, dst, cbase, esort);
    k_fine_fill_proj<<<NBUCKET, blk, 0, stream>>>(esort, bucket_base, col, row_ptr, dinv,
                                                  x, W_in, b_in, g0h);

    // layer 1: fused gather(g0)+GEMM -> g1 = fp16(dinv*relu(dinv*(s0@W1)+b1))
    k_gnn<64, 32, true, false><<<(N + 31) / 32, blk, 0, stream>>>(
        g0h, row_ptr, col, Wt1, b1, dinv, g1h, nullptr, nullptr, nullptr, N);

    // layer 2: fused gather(g1)+GEMM+pooling (no h2 materialization)
    k_gnn<128, 16, false, true><<<(N + 15) / 16, blk, 0, stream>>>(
        g1h, row_ptr, col, Wt2, b2, dinv, nullptr, batch, psum, pmax, N);

    // final MLP
    k_final<<<(N_GRAPHS * 256 + TB - 1) / TB, blk, 0, stream>>>(psum, pmax, pcnt, Wp, bp, out);
}

// Round 17
// 205.978 us; speedup vs baseline: 1.0578x; 1.0578x over previous
//
#include <hip/hip_runtime.h>
#include <hip/hip_fp16.h>

#define N_NODES 50000
#define N_EDGES 800000
#define N_GRAPHS 64
#define N_PAD 50048

#define CB 256                              // coarse-pass blocks
#define EPB (N_EDGES / CB)                  // 3125 edges per block (exact)
#define NBUCKET ((N_NODES + 255) / 256)     // 196 coarse buckets (dst>>8)

typedef _Float16 f16x8 __attribute__((ext_vector_type(8)));
typedef float f32x4 __attribute__((ext_vector_type(4)));

struct H8 { __half2 a, b, c, d; };

// ---------------- prep: weight transpose->fp16, pool zero, cursor zero ----------------

__global__ void k_prep(const float* __restrict__ W1, const float* __restrict__ W2,
                       _Float16* __restrict__ Wt1, _Float16* __restrict__ Wt2,
                       float* psum, float* pmax, int* totals) {
    int idx = blockIdx.x * blockDim.x + threadIdx.x;
    if (idx < 128 * 64) {                    // Wt1[n*64+k] = W1[k*128+n]
        int n = idx >> 6, k = idx & 63;
        Wt1[idx] = (_Float16)W1[k * 128 + n];
    } else if (idx < 128 * 64 + 128 * 128) { // Wt2[n*128+k] = W2[k*128+n]
        int j = idx - 128 * 64;
        int n = j >> 7, k = j & 127;
        Wt2[j] = (_Float16)W2[k * 128 + n];
    }
    if (idx < N_GRAPHS * 128) { psum[idx] = 0.f; pmax[idx] = 0.f; }
    if (idx < 256) totals[idx] = 0;
}

// ---------------- CSR build ----------------

__global__ __launch_bounds__(256) void k_coarse_hist(const int* __restrict__ dst,
                                                     int* __restrict__ totals) {
    __shared__ int hist[NBUCKET];
    int t = threadIdx.x, b = blockIdx.x;
    for (int i = t; i < NBUCKET; i += 256) hist[i] = 0;
    __syncthreads();
    int e0 = b * EPB;
    for (int e = e0 + t; e < e0 + EPB; e += 256)
        atomicAdd(&hist[dst[e] >> 8], 1);
    __syncthreads();
    for (int i = t; i < NBUCKET; i += 256)
        if (hist[i] > 0) atomicAdd(&totals[i], hist[i]);
}

// one block: exclusive scan of bucket totals; ALSO pcnt[g] via binary search on
// sorted batch (zero atomics)
__global__ void k_bucket_scan(const int* __restrict__ totals, int* __restrict__ bucket_base,
                              int* __restrict__ gcursor, const int* __restrict__ batch,
                              float* __restrict__ pcnt) {
    __shared__ int sh[256];
    int t = threadIdx.x;
    int v = (t < NBUCKET) ? totals[t] : 0;
    sh[t] = v;
    __syncthreads();
    for (int off = 1; off < 256; off <<= 1) {
        int u = (t >= off) ? sh[t - off] : 0;
        __syncthreads();
        sh[t] += u;
        __syncthreads();
    }
    if (t < NBUCKET) {
        int base = sh[t] - v;
        bucket_base[t] = base;
        gcursor[t] = base;
    }
    if (t == 0) bucket_base[NBUCKET] = N_EDGES;
    // pcnt via lower_bound: lb(g) = first i with batch[i] >= g
    if (t <= N_GRAPHS) {
        int lo = 0, hi = N_NODES;
        while (lo < hi) {
            int mid = (lo + hi) >> 1;
            if (batch[mid] < t) lo = mid + 1; else hi = mid;
        }
        sh[t] = lo;  // reuse sh (all scan reads done; threads t<=64 write disjoint)
    }
    __syncthreads();
    if (t < N_GRAPHS) pcnt[t] = (float)(sh[t + 1] - sh[t]);
}

// LDS hist -> atomic range reservation -> scatter packed ((dst&255)<<16 | src)
__global__ __launch_bounds__(256) void k_coarse_scatter(
        const int* __restrict__ src, const int* __restrict__ dst,
        int* __restrict__ gcursor, unsigned int* __restrict__ esort) {
    __shared__ int cur[NBUCKET];
    int t = threadIdx.x, b = blockIdx.x;
    for (int i = t; i < NBUCKET; i += 256) cur[i] = 0;
    __syncthreads();
    int e0 = b * EPB;
    for (int e = e0 + t; e < e0 + EPB; e += 256)
        atomicAdd(&cur[dst[e] >> 8], 1);
    __syncthreads();
    for (int i = t; i < NBUCKET; i += 256) {
        int cnt = cur[i];
        cur[i] = (cnt > 0) ? atomicAdd(&gcursor[i], cnt) : 0;  // reserve range
    }
    __syncthreads();
    for (int e = e0 + t; e < e0 + EPB; e += 256) {
        int d = dst[e];
        int slot = atomicAdd(&cur[d >> 8], 1);
        esort[slot] = ((unsigned)(d & 255) << 16) | (unsigned)src[e];  // src < 2^16
    }
}

// one block per bucket: fine hist -> row_ptr/dinv, cursor fill of col; fused input proj
__global__ __launch_bounds__(256) void k_fine_fill_proj(
        const unsigned int* __restrict__ esort, const int* __restrict__ bucket_base,
        int* __restrict__ col, int* __restrict__ row_ptr, float* __restrict__ dinv,
        const float* __restrict__ x, const float* __restrict__ W_in,
        const float* __restrict__ b_in, _Float16* __restrict__ g0) {
    __shared__ int hist[256];
    __shared__ int sc[256];
    __shared__ int cur[256];
    int t = threadIdx.x, b = blockIdx.x;
    hist[t] = 0;
    __syncthreads();
    int base = bucket_base[b], end = bucket_base[b + 1];
    for (int e = base + t; e < end; e += 256)
        atomicAdd(&hist[(esort[e] >> 16) & 255], 1);
    __syncthreads();
    int v = hist[t];
    sc[t] = v;
    __syncthreads();
    for (int off = 1; off < 256; off <<= 1) {
        int u = (t >= off) ? sc[t - off] : 0;
        __syncthreads();
        sc[t] += u;
        __syncthreads();
    }
    int start = base + sc[t] - v;
    cur[t] = start;
    int node = b * 256 + t;
    float di = rsqrtf((float)(v + 1));  // +1 self-loop
    if (node < N_NODES) {
        row_ptr[node] = start;
        dinv[node] = di;
    }
    if (b == 0 && t == 0) row_ptr[N_NODES] = N_EDGES;
    __syncthreads();
    for (int e = base + t; e < end; e += 256) {
        unsigned pk = esort[e];
        int slot = atomicAdd(&cur[(pk >> 16) & 255], 1);
        col[slot] = (int)(pk & 0xffffu);
    }
    // fused input projection for this block's node
    if (node < N_NODES) {
        float xr[6];
#pragma unroll
        for (int k = 0; k < 6; k++) xr[k] = x[node * 6 + k];
#pragma unroll
        for (int oc = 0; oc < 8; oc++) {  // 8 octets of 8 cols
            f16x8 o;
#pragma unroll
            for (int j = 0; j < 8; j++) {
                int cl = oc * 8 + j;
                float acc = b_in[cl];
#pragma unroll
                for (int k = 0; k < 6; k++) acc += xr[k] * W_in[k * 64 + cl];
                o[j] = (_Float16)(acc * di);
            }
            *(f16x8*)&g0[(size_t)node * 64 + oc * 8] = o;
        }
    }
}

// ---------------- fused gather + MFMA GEMM (+ optional fused pooling) ----------------
// ROWS=16 (K=128): 3125 blocks, 16 threads/row gather; wave w -> cols w*32..+32 (2 tiles)
// ROWS=32 (K=64): 1563 blocks, 8 threads/row gather; wave w -> rows (w&1)*16, cols (w>>1)*64
// POOL: stage epilogue values in LDS, column-threads reduce over the block's rows
// (batch sorted -> 1-2 graphs/block) and flush via atomics. No global h2 at all.
template <int K, int ROWS, bool HALF_OUT, bool POOL>
__global__ __launch_bounds__(256, 8) void k_gnn(
        const _Float16* __restrict__ g, const int* __restrict__ row_ptr,
        const int* __restrict__ col, const _Float16* __restrict__ Wt_h,
        const float* __restrict__ b, const float* __restrict__ dinv,
        void* __restrict__ outp, const int* __restrict__ batch,
        float* __restrict__ psum, float* __restrict__ pmax, int n) {
    constexpr int KP = K + 8;
    constexpr int TPR = 256 / ROWS;   // threads per row (16 or 8)
    constexpr int CO8 = K / 8;        // H8 chunks per row
    static_assert(K / TPR == 8, "8 channels per gather thread");
    constexpr int S_BYTES = ROWS * KP * 2;
    constexpr int H_BYTES = POOL ? ROWS * 128 * 4 : 0;
    constexpr int SMEM = S_BYTES > H_BYTES ? S_BYTES : H_BYTES;
    __shared__ __align__(16) char smem[SMEM];
    _Float16* Sl = (_Float16*)smem;
    float* Hs = (float*)smem;         // aliases Sl; used only after Sl is dead
    int t = threadIdx.x;

    // gather phase (4 loads in flight, 2 accumulator sets)
    {
        int row_local = t / TPR;
        int ck = t % TPR;             // which H8 chunk of the row
        int row = blockIdx.x * ROWS + row_local;
        float accA[8] = {};
        float accB[8] = {};
        const H8* gb = (const H8*)g;
        auto addv = [](float* acc, H8 v) {
            float2 f;
            f = __half22float2(v.a); acc[0] += f.x; acc[1] += f.y;
            f = __half22float2(v.b); acc[2] += f.x; acc[3] += f.y;
            f = __half22float2(v.c); acc[4] += f.x; acc[5] += f.y;
            f = __half22float2(v.d); acc[6] += f.x; acc[7] += f.y;
        };
        if (row < n) {
            addv(accA, gb[(size_t)row * CO8 + ck]);  // self term
            int e = row_ptr[row], e1 = row_ptr[row + 1];
            for (; e + 3 < e1; e += 4) {
                int c0 = col[e], c1 = col[e + 1], c2 = col[e + 2], c3 = col[e + 3];
                H8 v0 = gb[(size_t)c0 * CO8 + ck];
                H8 v1 = gb[(size_t)c1 * CO8 + ck];
                H8 v2 = gb[(size_t)c2 * CO8 + ck];
                H8 v3 = gb[(size_t)c3 * CO8 + ck];
                addv(accA, v0);
                addv(accB, v1);
                addv(accA, v2);
                addv(accB, v3);
            }
            if (e + 1 < e1) {
                H8 v0 = gb[(size_t)col[e] * CO8 + ck];
                H8 v1 = gb[(size_t)col[e + 1] * CO8 + ck];
                addv(accA, v0);
                addv(accB, v1);
                e += 2;
            }
            if (e < e1) addv(accA, gb[(size_t)col[e] * CO8 + ck]);
        }
        f16x8 o;
#pragma unroll
        for (int q = 0; q < 8; q++) o[q] = (_Float16)(accA[q] + accB[q]);
        *(f16x8*)&Sl[row_local * KP + ck * 8] = o;
    }
    __syncthreads();

    // MFMA phase
    int wave = t >> 6;
    int lane = t & 63;
    int m = lane & 15;
    int quad = lane >> 4;
    constexpr int COLT = (ROWS == 16) ? 2 : 4;  // column tiles per wave
    int col_base = (ROWS == 16) ? wave * 32 : (wave >> 1) * 64;
    int rbl = (ROWS == 16) ? 0 : (wave & 1) * 16;
    int wrow0 = blockIdx.x * ROWS + rbl;

    f32x4 acc[COLT] = {};
#pragma unroll
    for (int k0 = 0; k0 < K; k0 += 32) {
        f16x8 a = *(const f16x8*)&Sl[(rbl + m) * KP + k0 + quad * 8];
#pragma unroll
        for (int ct = 0; ct < COLT; ct++) {
            f16x8 bw = *(const f16x8*)(Wt_h + (size_t)(col_base + ct * 16 + m) * K + k0 + quad * 8);
            acc[ct] = __builtin_amdgcn_mfma_f32_16x16x32_f16(a, bw, acc[ct], 0, 0, 0);
        }
    }

    if (!POOL) {
#pragma unroll
        for (int r = 0; r < 4; r++) {
            int row = wrow0 + quad * 4 + r;
            if (row < n) {
                float di = dinv[row];
#pragma unroll
                for (int ct = 0; ct < COLT; ct++) {
                    int colb = col_base + ct * 16 + m;
                    float v = fmaxf(di * acc[ct][r] + b[colb], 0.f);
                    if (HALF_OUT)
                        ((_Float16*)outp)[(size_t)row * 128 + colb] = (_Float16)(v * di);
                    else
                        ((float*)outp)[(size_t)row * 128 + colb] = v;
                }
            }
        }
    } else {
        // fused pooling epilogue (ROWS==16): stage into Hs, reduce by sorted batch
        __syncthreads();  // all Sl reads complete before overwriting smem
#pragma unroll
        for (int r = 0; r < 4; r++) {
            int rl = quad * 4 + r;
            int row = wrow0 + rl;
            float di = (row < n) ? dinv[row] : 0.f;
#pragma unroll
            for (int ct = 0; ct < COLT; ct++) {
                int colb = col_base + ct * 16 + m;
                float v = fmaxf(di * acc[ct][r] + b[colb], 0.f);
                Hs[rl * 128 + colb] = (row < n) ? v : 0.f;
            }
        }
        __syncthreads();
        if (t < 128) {
            int colb = t;
            int row0b = blockIdx.x * ROWS;
            float s = 0.f, mx = 0.f;
            int gcur = batch[row0b < n ? row0b : (n - 1)];
            for (int rl = 0; rl < ROWS; rl++) {
                int row = row0b + rl;
                if (row >= n) break;
                int gi = batch[row];
                if (gi != gcur) {
                    atomicAdd(&psum[gcur * 128 + colb], s);
                    atomicMax((int*)&pmax[gcur * 128 + colb], __float_as_int(mx));
                    s = 0.f; mx = 0.f; gcur = gi;
                }
                float v = Hs[rl * 128 + colb];
                s += v;
                mx = fmaxf(mx, v);
            }
            atomicAdd(&psum[gcur * 128 + colb], s);
            atomicMax((int*)&pmax[gcur * 128 + colb], __float_as_int(mx));
        }
    }
}

// ---------------- final ----------------

__global__ void k_final(const float* __restrict__ psum, const float* __restrict__ pmax,
                        const float* __restrict__ pcnt, const float* __restrict__ Wp,
                        const float* __restrict__ bp, float* __restrict__ out) {
    int t = blockIdx.x * blockDim.x + threadIdx.x;
    if (t >= N_GRAPHS * 256) return;
    int g = t >> 8, j = t & 255;
    float inv = 1.0f / fmaxf(pcnt[g], 1.0f);
    float acc = bp[j];
#pragma unroll 4
    for (int k = 0; k < 128; k++) acc += (psum[g * 128 + k] * inv) * Wp[k * 256 + j];
#pragma unroll 4
    for (int k = 0; k < 128; k++) acc += pmax[g * 128 + k] * Wp[(128 + k) * 256 + j];
    out[t] = fmaxf(acc, 0.f);
}

extern "C" void kernel_launch(void* const* d_in, const int* in_sizes, int n_in,
                              void* d_out, int out_size, void* d_ws, size_t ws_size,
                              hipStream_t stream) {
    const int N = N_NODES, E = N_EDGES;
    const float* x    = (const float*)d_in[0];
    const int*   ei   = (const int*)d_in[1];
    const int*   src  = ei;
    const int*   dst  = ei + E;
    const int*   batch= (const int*)d_in[2];
    const float* W_in = (const float*)d_in[3];
    const float* b_in = (const float*)d_in[4];
    const float* W1   = (const float*)d_in[5];
    const float* b1   = (const float*)d_in[6];
    const float* W2   = (const float*)d_in[7];
    const float* b2   = (const float*)d_in[8];
    const float* Wp   = (const float*)d_in[9];
    const float* bp   = (const float*)d_in[10];
    float* out = (float*)d_out;

    char* p = (char*)d_ws;
    int* totals      = (int*)p;   p += 256 * 4;
    int* bucket_base = (int*)p;   p += 256 * 4;
    int* gcursor     = (int*)p;   p += 256 * 4;
    int* row_ptr     = (int*)p;   p += (N_PAD + 64) * 4;
    int* col         = (int*)p;   p += (size_t)N_EDGES * 4;
    unsigned* esort  = (unsigned*)p; p += (size_t)N_EDGES * 4;
    float* dinv      = (float*)p; p += N_PAD * 4;
    _Float16* Wt1    = (_Float16*)p; p += 128 * 64 * 2;
    _Float16* Wt2    = (_Float16*)p; p += 128 * 128 * 2;
    _Float16* g0h    = (_Float16*)p; p += (size_t)N_PAD * 64 * 2;
    _Float16* g1h    = (_Float16*)p; p += (size_t)N_PAD * 128 * 2;
    float* psum      = (float*)p; p += N_GRAPHS * 128 * 4;
    float* pmax      = (float*)p; p += N_GRAPHS * 128 * 4;
    float* pcnt      = (float*)p;

    const int TB = 256;
    dim3 blk(TB);

    // prep: weight transpose + pool/cursor zero
    k_prep<<<(128 * 64 + 128 * 128 + TB - 1) / TB, blk, 0, stream>>>(
        W1, W2, Wt1, Wt2, psum, pmax, totals);

    // CSR build (bucket_scan also computes pcnt by binary search — no atomics)
    k_coarse_hist<<<CB, blk, 0, stream>>>(dst, totals);
    k_bucket_scan<<<1, blk, 0, stream>>>(totals, bucket_base, gcursor, batch, pcnt);
    k_coarse_scatter<<<CB, blk, 0, stream>>>(src, dst, gcursor, esort);
    k_fine_fill_proj<<<NBUCKET, blk, 0, stream>>>(esort, bucket_base, col, row_ptr, dinv,
                                                  x, W_in, b_in, g0h);

    // layer 1: fused gather(g0)+GEMM -> g1 = fp16(dinv*relu(dinv*(s0@W1)+b1))
    k_gnn<64, 32, true, false><<<(N + 31) / 32, blk, 0, stream>>>(
        g0h, row_ptr, col, Wt1, b1, dinv, g1h, nullptr, nullptr, nullptr, N);

    // layer 2: fused gather(g1)+GEMM+pooling (no h2 materialization)
    k_gnn<128, 16, false, true><<<(N + 15) / 16, blk, 0, stream>>>(
        g1h, row_ptr, col, Wt2, b2, dinv, nullptr, batch, psum, pmax, N);

    // final MLP
    k_final<<<(N_GRAPHS * 256 + TB - 1) / TB, blk, 0, stream>>>(psum, pmax, pcnt, Wp, bp, out);
}